// Round 1
// baseline (854.837 us; speedup 1.0000x reference)
//
#include <hip/hip_runtime.h>
#include <hip/hip_bf16.h>

// DecoderRNN: attention is degenerate (enc seq len == 1 -> alpha == 1, awe == features).
// Pipeline: prep (cvt/transpose weights to bf16, gather embeddings, init h0/c0)
//   -> E-GEMM (emb part of gates, batched over all t)
//   -> 20 x (step1: gate/awe ; step2: gates GEMM + fused LSTM)
//   -> big masked GEMM h_state @ W_fc -> out.
// All GEMMs: bf16 MFMA 16x16x32, f32 accum; state kept f32; all NT layout.

#define BB 64
#define HH 512
#define VV 50257
#define VP 50304   // 393*128
#define TT 20

typedef __attribute__((ext_vector_type(4))) float f32x4;
typedef __attribute__((ext_vector_type(8))) short bf16x8;

#define MFMA(a,b,c) __builtin_amdgcn_mfma_f32_16x16x32_bf16((a),(b),(c),0,0,0)

__device__ __forceinline__ unsigned short f2bf(float f){
  union { float f; unsigned int u; } v; v.f = f;
  unsigned int u = v.u;
  unsigned int r = (u + 0x7FFFu + ((u >> 16) & 1u)) >> 16;
  return (unsigned short)r;
}
__device__ __forceinline__ float sigf(float x){ return 1.f/(1.f + expf(-x)); }

// ---------- prep kernels ----------

// Wcomb[j][0:512]=W_hh[j][:], Wcomb[j][512:1024]=W_ih[j][512:1024]; We[j][k]=W_ih[j][k<512]
__global__ __launch_bounds__(256) void cvt_weights(const float* __restrict__ Wih,
    const float* __restrict__ Whh, unsigned short* __restrict__ Wcomb,
    unsigned short* __restrict__ We){
  int j = blockIdx.x; int tid = threadIdx.x;
  for(int q=0;q<4;q++){ int k = tid + 256*q;
    float v = (k < 512) ? Whh[j*512 + k] : Wih[j*1024 + k];
    Wcomb[(size_t)j*1024 + k] = f2bf(v); }
  for(int q=0;q<2;q++){ int k = tid + 256*q;
    We[(size_t)j*512 + k] = f2bf(Wih[j*1024 + k]); }
}

// dst[c][r] = bf16(src[r][c]), src f32 [R][C], dst [Cpad][R], pad rows zeroed
__global__ __launch_bounds__(256) void transpose_cvt(const float* __restrict__ src,
    unsigned short* __restrict__ dst, int R, int C){
  __shared__ float tile[64][65];
  int c0 = blockIdx.x*64, r0 = blockIdx.y*64;
  int tx = threadIdx.x & 63, ty = threadIdx.x >> 6;
  for(int i=0;i<16;i++){
    int r = ty + i*4;
    int sc = c0 + tx;
    tile[r][tx] = (sc < C) ? src[(size_t)(r0+r)*C + sc] : 0.f;
  }
  __syncthreads();
  for(int i=0;i<16;i++){
    int cl = ty + i*4;
    dst[(size_t)(c0+cl)*R + r0 + tx] = f2bf(tile[tx][cl]);
  }
}

// EmbMat[m= t*64+b][k] = t==0 ? feat[b][k] : embed_table[cap[b][t-1]][k]  (bf16)
__global__ __launch_bounds__(128) void build_emb(const float* __restrict__ feat,
    const float* __restrict__ emb, const int* __restrict__ cap,
    unsigned short* __restrict__ EmbMat){
  int m = blockIdx.x; int t = m >> 6, b = m & 63;
  const float* src = (t == 0) ? (feat + b*512) : (emb + (size_t)cap[b*19 + (t-1)]*512);
  for(int q=0;q<4;q++){ int k = threadIdx.x + 128*q;
    EmbMat[(size_t)m*512 + k] = f2bf(src[k]); }
}

// h0/c0: features @ W_hinit/W_cinit + bias ; h0 -> x0 (bf16 h-part), c0 -> c (f32)
__global__ __launch_bounds__(512) void init_hc(const float* __restrict__ feat,
    const float* __restrict__ Whi, const float* __restrict__ bhi,
    const float* __restrict__ Wci, const float* __restrict__ bci,
    unsigned short* __restrict__ x0, float* __restrict__ c){
  int b = blockIdx.x; int j = threadIdx.x;
  float ah = bhi[j], ac = bci[j];
  for(int k=0;k<512;k++){
    float f = feat[b*512 + k];           // block-uniform -> scalar load
    ah += f * Whi[k*512 + j];
    ac += f * Wci[k*512 + j];
  }
  x0[b*1024 + j] = f2bf(ah);
  c[b*512 + j] = ac;
}

// ---------- generic 128x128 NT MFMA GEMM (K=512, row stride 512 both sides) ----------
// EPIL 0: E-GEMM  -> Cout[m*2048+n] = acc + bias1[n] + bias2[n]
// EPIL 1: preds   -> out[m*VV+n] = (t<len[b]) ? acc + bias1[n] : 0   (m = b*20+t, guard n<VV)
template<int EPIL>
__global__ __launch_bounds__(256) void gemm_nt(const unsigned short* __restrict__ Abf,
    const unsigned short* __restrict__ Bbf, const float* __restrict__ bias1,
    const float* __restrict__ bias2, const int* __restrict__ lens,
    float* __restrict__ Cout){
  __shared__ __align__(16) unsigned short As[128*64];
  __shared__ __align__(16) unsigned short Bs[128*64];
  const int n0 = blockIdx.x * 128;
  const int m0 = blockIdx.y * 128;
  const int tid = threadIdx.x;
  const int lane = tid & 63, w = tid >> 6;
  const int wr = w >> 1, wc = w & 1;
  f32x4 acc[4][4];
  for(int i=0;i<4;i++) for(int j=0;j<4;j++) acc[i][j] = f32x4{0.f,0.f,0.f,0.f};

  for(int k0=0;k0<512;k0+=64){
    __syncthreads();
    for(int q=0;q<4;q++){
      int chunk = tid + 256*q;             // 0..1023
      int row = chunk >> 3, c8 = (chunk & 7) * 8;
      *(bf16x8*)(As + row*64 + c8) = *(const bf16x8*)(Abf + (size_t)(m0+row)*512 + k0 + c8);
      *(bf16x8*)(Bs + row*64 + c8) = *(const bf16x8*)(Bbf + (size_t)(n0+row)*512 + k0 + c8);
    }
    __syncthreads();
    for(int kk=0;kk<64;kk+=32){
      bf16x8 af[4], bfv[4];
      for(int mf=0;mf<4;mf++)
        af[mf] = *(const bf16x8*)(As + (wr*64 + mf*16 + (lane&15))*64 + kk + (lane>>4)*8);
      for(int nf=0;nf<4;nf++)
        bfv[nf] = *(const bf16x8*)(Bs + (wc*64 + nf*16 + (lane&15))*64 + kk + (lane>>4)*8);
      for(int mf=0;mf<4;mf++)
        for(int nf=0;nf<4;nf++)
          acc[mf][nf] = MFMA(af[mf], bfv[nf], acc[mf][nf]);
    }
  }
  for(int mf=0;mf<4;mf++) for(int nf=0;nf<4;nf++){
    int n = n0 + wc*64 + nf*16 + (lane & 15);
    for(int r=0;r<4;r++){
      int m = m0 + wr*64 + mf*16 + (lane>>4)*4 + r;
      float v = acc[mf][nf][r];
      if constexpr (EPIL == 0){
        Cout[(size_t)m*2048 + n] = v + bias1[n] + bias2[n];
      } else {
        if(n < VV){
          int b = m / 20, t = m % 20;
          Cout[(size_t)m*VV + n] = (t < lens[b]) ? (v + bias1[n]) : 0.f;
        }
      }
    }
  }
}

// ---------- per-step kernels ----------

// step1: gate = sigmoid(h @ W_beta + b_beta); awe = gate * feat -> xcur awe-part (bf16)
// M=64(b) x N=64 per block (8 blocks), K=512. A = xcur h-part, B = Wbt (NT).
__global__ __launch_bounds__(256) void step1(const unsigned short* __restrict__ Wbt,
    const float* __restrict__ bbeta, const float* __restrict__ feat,
    unsigned short* __restrict__ xcur){
  __shared__ __align__(16) unsigned short As[64*64];
  __shared__ __align__(16) unsigned short Bs[64*64];
  int jj0 = blockIdx.x * 64;
  int tid = threadIdx.x, lane = tid & 63, w = tid >> 6;
  f32x4 acc[4];
  for(int i=0;i<4;i++) acc[i] = f32x4{0.f,0.f,0.f,0.f};
  for(int k0=0;k0<512;k0+=64){
    __syncthreads();
    for(int q=0;q<2;q++){
      int chunk = tid + 256*q;             // 0..511
      int row = chunk >> 3, c8 = (chunk & 7) * 8;
      *(bf16x8*)(As + row*64 + c8) = *(const bf16x8*)(xcur + row*1024 + k0 + c8);
      *(bf16x8*)(Bs + row*64 + c8) = *(const bf16x8*)(Wbt + (size_t)(jj0+row)*512 + k0 + c8);
    }
    __syncthreads();
    for(int kk=0;kk<64;kk+=32){
      bf16x8 af = *(const bf16x8*)(As + (w*16 + (lane&15))*64 + kk + (lane>>4)*8);
      for(int nf=0;nf<4;nf++){
        bf16x8 bv = *(const bf16x8*)(Bs + (nf*16 + (lane&15))*64 + kk + (lane>>4)*8);
        acc[nf] = MFMA(af, bv, acc[nf]);
      }
    }
  }
  for(int nf=0;nf<4;nf++) for(int r=0;r<4;r++){
    int b = w*16 + (lane>>4)*4 + r;
    int jj = jj0 + nf*16 + (lane & 15);
    float g = sigf(acc[nf][r] + bbeta[jj]);
    float awe = g * feat[b*512 + jj];
    xcur[b*1024 + 512 + jj] = f2bf(awe);
  }
}

// step2: gates = E[t] + [h|awe] @ Wcomb^T ; fused LSTM. Block tile: 64(b) x 64(n),
// n_local = gate*16 + jj_local so acc[nf] = gate nf for (b, jj). 32 blocks, K=1024.
__global__ __launch_bounds__(256) void step2(const unsigned short* __restrict__ Wcomb,
    const float* __restrict__ E, const unsigned short* __restrict__ xcur,
    unsigned short* __restrict__ xnext, float* __restrict__ c,
    unsigned short* __restrict__ hs, const int* __restrict__ lens, int t){
  __shared__ __align__(16) unsigned short As[64*64];
  __shared__ __align__(16) unsigned short Bs[64*64];
  int jj0 = blockIdx.x * 16;
  int tid = threadIdx.x, lane = tid & 63, w = tid >> 6;
  f32x4 acc[4];
  for(int i=0;i<4;i++) acc[i] = f32x4{0.f,0.f,0.f,0.f};
  for(int k0=0;k0<1024;k0+=64){
    __syncthreads();
    for(int q=0;q<2;q++){
      int chunk = tid + 256*q;
      int row = chunk >> 3, c8 = (chunk & 7) * 8;
      *(bf16x8*)(As + row*64 + c8) = *(const bf16x8*)(xcur + row*1024 + k0 + c8);
      int j = (row >> 4)*512 + jj0 + (row & 15);
      *(bf16x8*)(Bs + row*64 + c8) = *(const bf16x8*)(Wcomb + (size_t)j*1024 + k0 + c8);
    }
    __syncthreads();
    for(int kk=0;kk<64;kk+=32){
      bf16x8 af = *(const bf16x8*)(As + (w*16 + (lane&15))*64 + kk + (lane>>4)*8);
      for(int nf=0;nf<4;nf++){
        bf16x8 bv = *(const bf16x8*)(Bs + (nf*16 + (lane&15))*64 + kk + (lane>>4)*8);
        acc[nf] = MFMA(af, bv, acc[nf]);
      }
    }
  }
  for(int r=0;r<4;r++){
    int b = w*16 + (lane>>4)*4 + r;
    int jj = jj0 + (lane & 15);
    size_t eb = ((size_t)t*64 + b)*2048 + jj;
    float iv = sigf(acc[0][r] + E[eb]);
    float fv = sigf(acc[1][r] + E[eb + 512]);
    float gv = tanhf(acc[2][r] + E[eb + 1024]);
    float ov = sigf(acc[3][r] + E[eb + 1536]);
    float cold = c[b*512 + jj];
    float cnew = fv*cold + iv*gv;
    float hnew = ov * tanhf(cnew);
    bool valid = t < lens[b];
    if(valid) c[b*512 + jj] = cnew;
    hs[((size_t)b*20 + t)*512 + jj] = f2bf(hnew);        // unused rows masked to 0 later
    xnext[b*1024 + jj] = valid ? f2bf(hnew) : xcur[b*1024 + jj];
  }
}

// ---------- launcher ----------
extern "C" void kernel_launch(void* const* d_in, const int* in_sizes, int n_in,
                              void* d_out, int out_size, void* d_ws, size_t ws_size,
                              hipStream_t stream){
  const float* feat  = (const float*)d_in[0];
  const int*   cap   = (const int*)  d_in[1];
  const int*   lens  = (const int*)  d_in[2];
  const float* emb   = (const float*)d_in[3];
  const float* Wih   = (const float*)d_in[4];
  const float* Whh   = (const float*)d_in[5];
  const float* bih   = (const float*)d_in[6];
  const float* bhh   = (const float*)d_in[7];
  // d_in[8..13]: W_enc,b_enc,W_dec,b_dec,W_full,b_full -- dead (attention over seq len 1)
  const float* Whi   = (const float*)d_in[14];
  const float* bhi   = (const float*)d_in[15];
  const float* Wci   = (const float*)d_in[16];
  const float* bci   = (const float*)d_in[17];
  const float* Wbeta = (const float*)d_in[18];
  const float* bbeta = (const float*)d_in[19];
  const float* Wfc   = (const float*)d_in[20];
  const float* bfc   = (const float*)d_in[21];
  float* out = (float*)d_out;

  char* ws = (char*)d_ws;
  size_t off = 0;
  auto alloc = [&](size_t bytes)->void*{
    void* p = ws + off; off += (bytes + 1023) & ~(size_t)1023; return p; };
  unsigned short* Wcomb  = (unsigned short*)alloc((size_t)2048*1024*2); // [2048][1024]
  unsigned short* We     = (unsigned short*)alloc((size_t)2048*512*2);  // [2048][512]
  unsigned short* Wbt    = (unsigned short*)alloc((size_t)512*512*2);   // [512][512]
  unsigned short* Wfct   = (unsigned short*)alloc((size_t)VP*512*2);    // [50304][512]
  unsigned short* EmbMat = (unsigned short*)alloc((size_t)1280*512*2);  // [1280][512]
  float*          Emat   = (float*)alloc((size_t)1280*2048*4);          // [1280][2048]
  unsigned short* x0     = (unsigned short*)alloc((size_t)64*1024*2);
  unsigned short* x1     = (unsigned short*)alloc((size_t)64*1024*2);
  float*          cbuf   = (float*)alloc((size_t)64*512*4);
  unsigned short* hs     = (unsigned short*)alloc((size_t)1280*512*2);  // [b*20+t][512]

  cvt_weights<<<2048, 256, 0, stream>>>(Wih, Whh, Wcomb, We);
  transpose_cvt<<<dim3(8,8),    256, 0, stream>>>(Wbeta, Wbt, 512, 512);
  transpose_cvt<<<dim3(786,8),  256, 0, stream>>>(Wfc,  Wfct, 512, VV);
  build_emb<<<1280, 128, 0, stream>>>(feat, emb, cap, EmbMat);
  init_hc<<<64, 512, 0, stream>>>(feat, Whi, bhi, Wci, bci, x0, cbuf);

  // E = emb-part of gates + b_ih + b_hh, all t at once: M=1280, N=2048, K=512
  gemm_nt<0><<<dim3(16,10), 256, 0, stream>>>(EmbMat, We, bih, bhh, nullptr, Emat);

  for(int t=0;t<TT;t++){
    unsigned short* xc = (t & 1) ? x1 : x0;
    unsigned short* xn = (t & 1) ? x0 : x1;
    step1<<<8,  256, 0, stream>>>(Wbt, bbeta, feat, xc);
    step2<<<32, 256, 0, stream>>>(Wcomb, Emat, xc, xn, cbuf, hs, lens, t);
  }

  // preds: out[b*20+t][n] = mask ? hs @ Wfc + b_fc : 0 ; M=1280, N=50304(pad), K=512
  gemm_nt<1><<<dim3(393,10), 256, 0, stream>>>(hs, Wfct, bfc, nullptr, lens, out);
}